// Round 1
// baseline (603.561 us; speedup 1.0000x reference)
//
#include <hip/hip_runtime.h>

// Problem constants
#define BATCH 64
#define SEQ   4096
#define DECD  512
#define ENC   256
#define TS    128            // positions per block in main kernel
#define NCHUNK (SEQ / TS)    // 32 chunks per batch
#define OUT_ATTN (BATCH * ENC)  // offset of attn region in d_out

typedef short  short8  __attribute__((ext_vector_type(8)));
typedef float  floatx4 __attribute__((ext_vector_type(4)));

__device__ __forceinline__ short f2bf(float f) {
    // round-to-nearest-even fp32 -> bf16 (inputs are normal values)
    union { float f; unsigned u; } v; v.f = f;
    unsigned u = v.u;
    u += 0x7FFFu + ((u >> 16) & 1u);
    return (short)(u >> 16);
}

__device__ __forceinline__ float fast_tanh(float x) {
    // tanh(x) = (e^{2x}-1)/(e^{2x}+1), clamped to avoid inf/inf
    x = fminf(fmaxf(x, -9.0f), 9.0f);
    float e2 = __expf(2.0f * x);
    return (e2 - 1.0f) / (e2 + 1.0f);
}

// Kernel 1: dpb[b][e] = sum_d dh[b,d] * Wd[d,e] + bd[e] + be[e]   (fp32)
__global__ void dp_kernel(const float* __restrict__ dh,
                          const float* __restrict__ Wd,
                          const float* __restrict__ bd,
                          const float* __restrict__ be,
                          float* __restrict__ dpb) {
    __shared__ float dhs[DECD];
    int b = blockIdx.x, t = threadIdx.x;
    dhs[t]       = dh[b * DECD + t];
    dhs[t + 256] = dh[b * DECD + t + 256];
    __syncthreads();
    float acc = bd[t] + be[t];
#pragma unroll 8
    for (int d = 0; d < DECD; ++d)
        acc = fmaf(dhs[d], Wd[d * ENC + t], acc);
    dpb[b * ENC + t] = acc;
}

// Kernel 2: pack We (fp32 [K=256][N=256]) into bf16 MFMA B-fragment layout:
// WeF[((kt*16+nt)*64+lane)*8 + j] = bf16( We[kt*32 + (lane>>4)*8 + j][nt*16 + (lane&15)] )
__global__ void pack_kernel(const float* __restrict__ We, short* __restrict__ WeF) {
    int gid  = blockIdx.x * 256 + threadIdx.x;   // 0..8191
    int lane = gid & 63;
    int nt   = (gid >> 6) & 15;
    int kt   = gid >> 10;
    int quad = lane >> 4, l16 = lane & 15;
    int n = nt * 16 + l16;
    short8 v;
#pragma unroll
    for (int j = 0; j < 8; ++j) {
        int k = kt * 32 + quad * 8 + j;
        v[j] = f2bf(We[k * ENC + n]);
    }
    *(short8*)(WeF + gid * 8) = v;
}

// Kernel 3 (main): per block = (batch b, chunk of 128 positions):
//   P = enc_tile @ We  (MFMA bf16, fp32 acc)
//   score = Wa . tanh(P + dpb[b]) + ba, masked
//   block-local online softmax partial: m, l, ctx = sum w_s * enc[s]
__global__ __launch_bounds__(256, 2) void main_kernel(
    const float* __restrict__ enc, const int* __restrict__ mask,
    const short* __restrict__ WeF, const float* __restrict__ dpb,
    const float* __restrict__ Wa, const float* __restrict__ ba,
    float* __restrict__ out, float* __restrict__ ctx_ws, float* __restrict__ ml_ws)
{
    int blk   = blockIdx.x;
    int b     = blk >> 5;      // / NCHUNK
    int chunk = blk & 31;
    int s_base = chunk * TS;
    int t    = threadIdx.x;
    int wave = t >> 6, lane = t & 63;
    int quad = lane >> 4, l16 = lane & 15;

    __shared__ float sc[TS];
    __shared__ float wgt[TS];

    const float* encB = enc + (size_t)b * SEQ * ENC;

    floatx4 acc[2][16];
#pragma unroll
    for (int mt = 0; mt < 2; ++mt)
#pragma unroll
        for (int nt = 0; nt < 16; ++nt)
            acc[mt][nt] = (floatx4){0.f, 0.f, 0.f, 0.f};

    // A-fragment source rows: wave covers 32 positions (2 M-tiles of 16)
    int row0 = s_base + wave * 32 + l16;   // mt = 0
    int row1 = row0 + 16;                  // mt = 1
    const float* aptr0 = encB + row0 * ENC + quad * 8;
    const float* aptr1 = encB + row1 * ENC + quad * 8;

    for (int kt = 0; kt < 8; ++kt) {
        floatx4 x0 = *(const floatx4*)(aptr0 + kt * 32);
        floatx4 x1 = *(const floatx4*)(aptr0 + kt * 32 + 4);
        floatx4 y0 = *(const floatx4*)(aptr1 + kt * 32);
        floatx4 y1 = *(const floatx4*)(aptr1 + kt * 32 + 4);
        short8 a0, a1;
#pragma unroll
        for (int j = 0; j < 4; ++j) {
            a0[j]     = f2bf(x0[j]);
            a0[j + 4] = f2bf(x1[j]);
            a1[j]     = f2bf(y0[j]);
            a1[j + 4] = f2bf(y1[j]);
        }
        const short* wp = WeF + (size_t)(kt * 16 * 64 + lane) * 8;
#pragma unroll
        for (int nt = 0; nt < 16; ++nt) {
            short8 bf = *(const short8*)(wp + (size_t)nt * 64 * 8);
            acc[0][nt] = __builtin_amdgcn_mfma_f32_16x16x32_bf16(a0, bf, acc[0][nt], 0, 0, 0);
            acc[1][nt] = __builtin_amdgcn_mfma_f32_16x16x32_bf16(a1, bf, acc[1][nt], 0, 0, 0);
        }
    }

    // Epilogue: energy = tanh(acc + dpb[n]); per-row score partial = sum_n Wa[n]*energy
    float ba0 = ba[0];
    float part[2][4] = {{0.f, 0.f, 0.f, 0.f}, {0.f, 0.f, 0.f, 0.f}};
#pragma unroll
    for (int nt = 0; nt < 16; ++nt) {
        int n = nt * 16 + l16;
        float wa  = Wa[n];
        float dpv = dpb[b * ENC + n];
#pragma unroll
        for (int mt = 0; mt < 2; ++mt)
#pragma unroll
            for (int r = 0; r < 4; ++r) {
                float th = fast_tanh(acc[mt][nt][r] + dpv);
                part[mt][r] = fmaf(wa, th, part[mt][r]);
            }
    }

    // reduce across the 16 lanes of each quad (cols) -> per-row scores
#pragma unroll
    for (int mt = 0; mt < 2; ++mt) {
#pragma unroll
        for (int r = 0; r < 4; ++r) {
            float v = part[mt][r];
            v += __shfl_xor(v, 1);
            v += __shfl_xor(v, 2);
            v += __shfl_xor(v, 4);
            v += __shfl_xor(v, 8);
            part[mt][r] = v;
        }
        if (l16 == 0) {
            int idx0 = wave * 32 + mt * 16 + quad * 4;   // local row of first reg
            int s0 = s_base + idx0;
            const int4 mv = *(const int4*)(mask + b * SEQ + s0);
            int mvals[4] = {mv.x, mv.y, mv.z, mv.w};
#pragma unroll
            for (int r = 0; r < 4; ++r) {
                float scv = part[mt][r] + ba0;
                if (mvals[r] == 0) scv = -1e10f;
                sc[idx0 + r] = scv;
                out[OUT_ATTN + b * SEQ + s0 + r] = scv;   // raw masked score (normalized later)
            }
        }
    }
    __syncthreads();

    // block-local softmax partial (uniform LDS broadcast loops)
    float m = sc[0];
#pragma unroll 8
    for (int i = 1; i < TS; ++i) m = fmaxf(m, sc[i]);
    if (t < TS) wgt[t] = __expf(sc[t] - m);
    __syncthreads();
    float l = 0.f;
#pragma unroll 8
    for (int i = 0; i < TS; ++i) l += wgt[i];

    // unnormalized context partial: ctx[e] = sum_s w_s * enc[s][e]  (tile is L2-hot)
    float ctx = 0.f;
    const float* ep = encB + (size_t)s_base * ENC + t;
#pragma unroll 4
    for (int s2 = 0; s2 < TS; ++s2)
        ctx = fmaf(wgt[s2], ep[(size_t)s2 * ENC], ctx);

    int cidx = b * NCHUNK + chunk;
    ctx_ws[(size_t)cidx * ENC + t] = ctx;
    if (t == 0) {
        ml_ws[cidx * 2]     = m;
        ml_ws[cidx * 2 + 1] = l;
    }
}

// Kernel 4: combine chunk partials per batch; finalize context and attn
__global__ void final_kernel(const float* __restrict__ ctx_ws,
                             const float* __restrict__ ml_ws,
                             float* __restrict__ out) {
    int b = blockIdx.x, t = threadIdx.x;
    float m = -3.4e38f;
    for (int c = 0; c < NCHUNK; ++c)
        m = fmaxf(m, ml_ws[(b * NCHUNK + c) * 2]);
    float L = 0.f;
    for (int c = 0; c < NCHUNK; ++c)
        L += ml_ws[(b * NCHUNK + c) * 2 + 1] * __expf(ml_ws[(b * NCHUNK + c) * 2] - m);
    float inv = 1.0f / L;

    float cx = 0.f;
    for (int c = 0; c < NCHUNK; ++c)
        cx += ctx_ws[(size_t)(b * NCHUNK + c) * ENC + t] * __expf(ml_ws[(b * NCHUNK + c) * 2] - m);
    out[b * ENC + t] = cx * inv;

    for (int s = t; s < SEQ; s += 256) {
        float raw = out[OUT_ATTN + b * SEQ + s];
        out[OUT_ATTN + b * SEQ + s] = __expf(raw - m) * inv;
    }
}

extern "C" void kernel_launch(void* const* d_in, const int* in_sizes, int n_in,
                              void* d_out, int out_size, void* d_ws, size_t ws_size,
                              hipStream_t stream) {
    const float* dh   = (const float*)d_in[0];
    const float* enc  = (const float*)d_in[1];
    const int*   mask = (const int*)d_in[2];
    const float* Wd   = (const float*)d_in[3];
    const float* bd   = (const float*)d_in[4];
    const float* We   = (const float*)d_in[5];
    const float* be   = (const float*)d_in[6];
    const float* Wa   = (const float*)d_in[7];
    const float* ba   = (const float*)d_in[8];
    float* out = (float*)d_out;

    // workspace layout (floats): ctx_ws[64*32*256] | ml_ws[64*32*2] | dpb[64*256] | WeF (bf16, 64K shorts)
    float* w      = (float*)d_ws;
    float* ctx_ws = w;
    float* ml_ws  = w + BATCH * NCHUNK * ENC;
    float* dpb    = ml_ws + BATCH * NCHUNK * 2;
    short* WeF    = (short*)(dpb + BATCH * ENC);

    hipLaunchKernelGGL(dp_kernel,   dim3(BATCH),          dim3(256), 0, stream, dh, Wd, bd, be, dpb);
    hipLaunchKernelGGL(pack_kernel, dim3(32),             dim3(256), 0, stream, We, WeF);
    hipLaunchKernelGGL(main_kernel, dim3(BATCH * NCHUNK), dim3(256), 0, stream,
                       enc, mask, WeF, dpb, Wa, ba, out, ctx_ws, ml_ws);
    hipLaunchKernelGGL(final_kernel, dim3(BATCH),         dim3(256), 0, stream, ctx_ws, ml_ws, out);
}

// Round 2
// 444.079 us; speedup vs baseline: 1.3591x; 1.3591x over previous
//
#include <hip/hip_runtime.h>

#define BATCH 64
#define SEQ   4096
#define DECD  512
#define ENC   256
#define TS    64                 // positions per block in main kernel
#define NCHUNK (SEQ / TS)        // 64 chunks per batch
#define OUT_ATTN (BATCH * ENC)   // offset of attn region in d_out

typedef short  short8  __attribute__((ext_vector_type(8)));
typedef float  floatx4 __attribute__((ext_vector_type(4)));

__device__ __forceinline__ short f2bf(float f) {
    union { float f; unsigned u; } v; v.f = f;
    unsigned u = v.u;
    u += 0x7FFFu + ((u >> 16) & 1u);
    return (short)(u >> 16);
}

__device__ __forceinline__ float fast_tanh(float x) {
    // tanh(x) = 1 - 2/(e^{2x}+1); v_rcp_f32 approx (~1 ulp) is plenty for bf16-level tol
    x = fminf(fmaxf(x, -9.0f), 9.0f);
    float e2 = __expf(2.0f * x);
    float r  = __builtin_amdgcn_rcpf(e2 + 1.0f);
    return fmaf(-2.0f, r, 1.0f);
}

// async global->LDS, 16B per lane. LDS dest = wave-uniform base + lane*16.
__device__ __forceinline__ void gload_lds16(const short* g, short* l) {
    __builtin_amdgcn_global_load_lds(
        (const __attribute__((address_space(1))) unsigned int*)g,
        (__attribute__((address_space(3))) unsigned int*)l,
        16, 0, 0);
}

// Kernel 1: dpb[b][e] = sum_d dh[b,d] * Wd[d,e] + bd[e] + be[e]   (fp32)
__global__ void dp_kernel(const float* __restrict__ dh,
                          const float* __restrict__ Wd,
                          const float* __restrict__ bd,
                          const float* __restrict__ be,
                          float* __restrict__ dpb) {
    __shared__ float dhs[DECD];
    int b = blockIdx.x, t = threadIdx.x;
    dhs[t]       = dh[b * DECD + t];
    dhs[t + 256] = dh[b * DECD + t + 256];
    __syncthreads();
    float a0 = 0.f, a1 = 0.f, a2 = 0.f, a3 = 0.f;   // 4 chains -> deep load pipeline
#pragma unroll 4
    for (int d = 0; d < DECD; d += 4) {
        a0 = fmaf(dhs[d],     Wd[(d)     * ENC + t], a0);
        a1 = fmaf(dhs[d + 1], Wd[(d + 1) * ENC + t], a1);
        a2 = fmaf(dhs[d + 2], Wd[(d + 2) * ENC + t], a2);
        a3 = fmaf(dhs[d + 3], Wd[(d + 3) * ENC + t], a3);
    }
    dpb[b * ENC + t] = bd[t] + be[t] + ((a0 + a1) + (a2 + a3));
}

// Kernel 2: pack We (fp32 [K=256][N=256]) into bf16 MFMA B-fragment layout:
// WeF[((kt*16+nt)*64+lane)*8 + j] = bf16( We[kt*32 + (lane>>4)*8 + j][nt*16 + (lane&15)] )
// -> each kt slice is a contiguous 16KB chunk (stageable linearly into LDS).
__global__ void pack_kernel(const float* __restrict__ We, short* __restrict__ WeF) {
    int gid  = blockIdx.x * 256 + threadIdx.x;   // 0..8191
    int lane = gid & 63;
    int nt   = (gid >> 6) & 15;
    int kt   = gid >> 10;
    int quad = lane >> 4, l16 = lane & 15;
    int n = nt * 16 + l16;
    short8 v;
#pragma unroll
    for (int j = 0; j < 8; ++j) {
        int k = kt * 32 + quad * 8 + j;
        v[j] = f2bf(We[k * ENC + n]);
    }
    *(short8*)(WeF + gid * 8) = v;
}

// Kernel 3 (main): block = (batch b, chunk of 64 positions); wave = one 16-row M-tile.
__global__ __launch_bounds__(256, 4) void main_kernel(
    const float* __restrict__ enc, const int* __restrict__ mask,
    const short* __restrict__ WeF, const float* __restrict__ dpb,
    const float* __restrict__ Wa, const float* __restrict__ ba,
    float* __restrict__ out, float* __restrict__ ctx_ws, float* __restrict__ ml_ws)
{
    __shared__ short bsl[2][8192];   // double-buffered 16KB WeF k-slice
    __shared__ float sc[TS];
    __shared__ float dpbs[ENC];
    __shared__ float was[ENC];

    int blk   = blockIdx.x;
    int b     = blk >> 6;            // / NCHUNK
    int chunk = blk & 63;
    int s_base = chunk * TS;
    int t    = threadIdx.x;
    int w    = t >> 6, lane = t & 63;
    int quad = lane >> 4, l16 = lane & 15;

    const float* encB = enc + (size_t)b * SEQ * ENC;
    int row = s_base + w * 16 + l16;
    const float* aRow = encB + (size_t)row * ENC + quad * 8;

    // preload small per-block vectors into LDS
    dpbs[t] = dpb[b * ENC + t];
    was[t]  = Wa[t];

    floatx4 acc[16];
#pragma unroll
    for (int nt = 0; nt < 16; ++nt) acc[nt] = (floatx4){0.f, 0.f, 0.f, 0.f};

    // stage slice 0 (async; 4 x 16B per thread; lds layout == linear global order)
#pragma unroll
    for (int j = 0; j < 4; ++j)
        gload_lds16(WeF + j * 2048 + (w * 64 + lane) * 8, &bsl[0][0] + j * 2048 + w * 512);

    // A-tile regs for kt=0
    floatx4 x0 = *(const floatx4*)(aRow);
    floatx4 x1 = *(const floatx4*)(aRow + 4);

    for (int kt = 0; kt < 8; ++kt) {
        __syncthreads();   // vmcnt drain: slice kt staged + all waves done reading buf[(kt+1)&1]
        if (kt < 7) {
            // issue next B slice AFTER the barrier so it overlaps this kt's compute
            const short* g = WeF + (kt + 1) * 8192;
            short* lb = &bsl[(kt + 1) & 1][0];
#pragma unroll
            for (int j = 0; j < 4; ++j)
                gload_lds16(g + j * 2048 + (w * 64 + lane) * 8, lb + j * 2048 + w * 512);
        }
        floatx4 nx0, nx1;
        if (kt < 7) {       // prefetch next A chunk
            nx0 = *(const floatx4*)(aRow + (kt + 1) * 32);
            nx1 = *(const floatx4*)(aRow + (kt + 1) * 32 + 4);
        }
        short8 a;
#pragma unroll
        for (int j = 0; j < 4; ++j) { a[j] = f2bf(x0[j]); a[j + 4] = f2bf(x1[j]); }
        const short* bp = &bsl[kt & 1][0] + lane * 8;
#pragma unroll
        for (int nt = 0; nt < 16; ++nt) {
            short8 bf = *(const short8*)(bp + nt * 512);
            acc[nt] = __builtin_amdgcn_mfma_f32_16x16x32_bf16(a, bf, acc[nt], 0, 0, 0);
        }
        if (kt < 7) { x0 = nx0; x1 = nx1; }
    }

    // Epilogue: score_row = ba + sum_n Wa[n]*tanh(P[row][n] + dpb[n])
    float ba0 = ba[0];
    float part[4] = {0.f, 0.f, 0.f, 0.f};
#pragma unroll
    for (int nt = 0; nt < 16; ++nt) {
        int n = nt * 16 + l16;
        float wa  = was[n];
        float dpv = dpbs[n];
#pragma unroll
        for (int r = 0; r < 4; ++r)
            part[r] = fmaf(wa, fast_tanh(acc[nt][r] + dpv), part[r]);
    }
#pragma unroll
    for (int r = 0; r < 4; ++r) {   // reduce over the 16 column-lanes
        float v = part[r];
        v += __shfl_xor(v, 1);
        v += __shfl_xor(v, 2);
        v += __shfl_xor(v, 4);
        v += __shfl_xor(v, 8);
        part[r] = v;
    }
    if (l16 == 0) {
        int idx0 = w * 16 + quad * 4;     // local row of reg r=0
        int s0 = s_base + idx0;
        const int4 mv = *(const int4*)(mask + b * SEQ + s0);
        int mvals[4] = {mv.x, mv.y, mv.z, mv.w};
#pragma unroll
        for (int r = 0; r < 4; ++r) {
            float scv = part[r] + ba0;
            if (mvals[r] == 0) scv = -1e10f;
            sc[idx0 + r] = scv;
            out[OUT_ATTN + (size_t)b * SEQ + s0 + r] = scv;   // raw score; final normalizes
        }
    }
    __syncthreads();

    // block softmax partials: every wave redundantly reduces the 64 scores via shuffles
    float v = sc[lane];
    float m = v;
    m = fmaxf(m, __shfl_xor(m, 1));
    m = fmaxf(m, __shfl_xor(m, 2));
    m = fmaxf(m, __shfl_xor(m, 4));
    m = fmaxf(m, __shfl_xor(m, 8));
    m = fmaxf(m, __shfl_xor(m, 16));
    m = fmaxf(m, __shfl_xor(m, 32));
    float e = __expf(v - m);          // lane s holds weight of position s
    float l = e;
    l += __shfl_xor(l, 1);
    l += __shfl_xor(l, 2);
    l += __shfl_xor(l, 4);
    l += __shfl_xor(l, 8);
    l += __shfl_xor(l, 16);
    l += __shfl_xor(l, 32);

    // unnormalized context partial: ctx[e] = sum_s w_s * enc[s][e]  (rows L1/L2-hot)
    float c0 = 0.f, c1 = 0.f, c2 = 0.f, c3 = 0.f;
    const float* ep = encB + (size_t)s_base * ENC + t;
#pragma unroll 4
    for (int s2 = 0; s2 < TS; s2 += 4) {
        float w0 = __shfl(e, s2);
        float w1 = __shfl(e, s2 + 1);
        float w2 = __shfl(e, s2 + 2);
        float w3 = __shfl(e, s2 + 3);
        c0 = fmaf(w0, ep[(size_t)(s2)     * ENC], c0);
        c1 = fmaf(w1, ep[(size_t)(s2 + 1) * ENC], c1);
        c2 = fmaf(w2, ep[(size_t)(s2 + 2) * ENC], c2);
        c3 = fmaf(w3, ep[(size_t)(s2 + 3) * ENC], c3);
    }
    float ctx = (c0 + c1) + (c2 + c3);

    int cidx = b * NCHUNK + chunk;
    ctx_ws[(size_t)cidx * ENC + t] = ctx;
    if (t == 0) {
        ml_ws[cidx * 2]     = m;
        ml_ws[cidx * 2 + 1] = l;
    }
}

// Kernel 4: combine chunk partials per batch; finalize context and attn
__global__ void final_kernel(const float* __restrict__ ctx_ws,
                             const float* __restrict__ ml_ws,
                             float* __restrict__ out) {
    int b = blockIdx.x, t = threadIdx.x;
    float m = -3.4e38f;
    for (int c = 0; c < NCHUNK; ++c)
        m = fmaxf(m, ml_ws[(b * NCHUNK + c) * 2]);
    float L = 0.f;
    for (int c = 0; c < NCHUNK; ++c)
        L += ml_ws[(b * NCHUNK + c) * 2 + 1] * __expf(ml_ws[(b * NCHUNK + c) * 2] - m);
    float inv = 1.0f / L;

    float cx = 0.f;
    for (int c = 0; c < NCHUNK; ++c)
        cx += ctx_ws[(size_t)(b * NCHUNK + c) * ENC + t] * __expf(ml_ws[(b * NCHUNK + c) * 2] - m);
    out[b * ENC + t] = cx * inv;

    for (int s = t; s < SEQ; s += 256) {
        float raw = out[OUT_ATTN + (size_t)b * SEQ + s];
        out[OUT_ATTN + (size_t)b * SEQ + s] = __expf(raw - m) * inv;
    }
}

extern "C" void kernel_launch(void* const* d_in, const int* in_sizes, int n_in,
                              void* d_out, int out_size, void* d_ws, size_t ws_size,
                              hipStream_t stream) {
    const float* dh   = (const float*)d_in[0];
    const float* enc  = (const float*)d_in[1];
    const int*   mask = (const int*)d_in[2];
    const float* Wd   = (const float*)d_in[3];
    const float* bd   = (const float*)d_in[4];
    const float* We   = (const float*)d_in[5];
    const float* be   = (const float*)d_in[6];
    const float* Wa   = (const float*)d_in[7];
    const float* ba   = (const float*)d_in[8];
    float* out = (float*)d_out;

    // ws layout (floats): ctx_ws[64*64*256] | ml_ws[64*64*2] | dpb[64*256] | WeF (bf16, 64K shorts)
    float* w      = (float*)d_ws;
    float* ctx_ws = w;
    float* ml_ws  = w + BATCH * NCHUNK * ENC;
    float* dpbuf  = ml_ws + BATCH * NCHUNK * 2;
    short* WeF    = (short*)(dpbuf + BATCH * ENC);

    hipLaunchKernelGGL(dp_kernel,   dim3(BATCH),           dim3(256), 0, stream, dh, Wd, bd, be, dpbuf);
    hipLaunchKernelGGL(pack_kernel, dim3(32),              dim3(256), 0, stream, We, WeF);
    hipLaunchKernelGGL(main_kernel, dim3(BATCH * NCHUNK),  dim3(256), 0, stream,
                       enc, mask, WeF, dpbuf, Wa, ba, out, ctx_ws, ml_ws);
    hipLaunchKernelGGL(final_kernel, dim3(BATCH),          dim3(256), 0, stream, ctx_ws, ml_ws, out);
}